// Round 2
// baseline (345.076 us; speedup 1.0000x reference)
//
#include <hip/hip_runtime.h>

#define DIM 144
#define ROWS 64
#define TILE_ELEMS (ROWS * DIM)        // 9216 floats per tile
#define TILE_F4 (TILE_ELEMS / 4)       // 2304 float4 per tile
#define F4_PER_THREAD (TILE_F4 / 256)  // 9
#define PERSIST_BLOCKS 1024            // ~4 blocks/CU on 256 CUs

// ---------------------------------------------------------------------------
// Kernel 1: build Cw[9][16][16] — per-(l,t)-unit 16x16 mixing matrices.
// C[p][v][u] = mixing[k, i0, j0] * norm[i0, j0] * weight[k]
// k = l*256 + v*16 + u (reference path order), i0 = off+v*d+t, j0 = off+u*d+t.
// ---------------------------------------------------------------------------
__global__ __launch_bounds__(256) void build_C(
    const float* __restrict__ weight,
    const float* __restrict__ mixing,
    const float* __restrict__ norm,
    float* __restrict__ Cw)
{
    int idx = blockIdx.x * 256 + threadIdx.x;   // 0 .. 2303
    if (idx >= 9 * 256) return;
    int p  = idx >> 8;          // unit 0..8
    int vu = idx & 255;
    int v = vu >> 4, u = vu & 15;
    int l, t, off;
    if (p == 0)      { l = 0; t = 0;     off = 0;  }
    else if (p < 4)  { l = 1; t = p - 1; off = 16; }
    else             { l = 2; t = p - 4; off = 64; }
    int d  = 2 * l + 1;
    int k  = l * 256 + v * 16 + u;
    int i0 = off + v * d + t;
    int j0 = off + u * d + t;
    float m  = mixing[(size_t)k * (DIM * DIM) + i0 * DIM + j0];
    float nc = norm[i0 * DIM + j0];
    Cw[idx] = m * nc * weight[k];
}

// ---------------------------------------------------------------------------
// Kernel 2: persistent, software-pipelined transpose-mix-transpose.
// Grid-stride over 64-row tiles; while tile t computes/stores, tile t+stride's
// 9 coalesced float4 loads are already in flight in a second register buffer.
// LDS layout (XOR swizzle, no padding, 36 KB):
//   addr(col,row) = col*64 + (row ^ (col>>2))   -> compute reads conflict-free
// ---------------------------------------------------------------------------
__device__ __forceinline__ void unit_params(int p, int& d, int& t, int& off) {
    int l;
    if (p == 0)      { l = 0; t = 0;     off = 0;  }
    else if (p < 4)  { l = 1; t = p - 1; off = 16; }
    else             { l = 2; t = p - 4; off = 64; }
    d = 2 * l + 1;
}

__device__ __forceinline__ void load_tile(
    const float4* __restrict__ feat4, long long base4, long long total4,
    int tid, float4 v[F4_PER_THREAD])
{
    if (base4 + TILE_F4 <= total4) {
#pragma unroll
        for (int i = 0; i < F4_PER_THREAD; ++i)
            v[i] = feat4[base4 + i * 256 + tid];
    } else {
#pragma unroll
        for (int i = 0; i < F4_PER_THREAD; ++i) {
            long long g = base4 + i * 256 + tid;
            v[i] = (g < total4) ? feat4[g] : make_float4(0.f, 0.f, 0.f, 0.f);
        }
    }
}

__global__ __launch_bounds__(256, 4) void tp_linear_kernel(
    const float4* __restrict__ feat4,
    const float* __restrict__ Cw,
    float4* __restrict__ out4,
    long long total4,
    int tiles)
{
    __shared__ float buf[DIM * 64];
    const int tid = threadIdx.x;
    const int nb  = gridDim.x;
    const int r   = tid & 63;
    const int w   = tid >> 6;

    int t = blockIdx.x;
    if (t >= tiles) return;

    float4 va[F4_PER_THREAD], vb[F4_PER_THREAD];
    load_tile(feat4, (long long)t * TILE_F4, total4, tid, va);

    for (; t < tiles; t += nb) {
        // ---- stage in: swizzled b32 LDS writes from prefetched registers ----
#pragma unroll
        for (int i = 0; i < F4_PER_THREAD; ++i) {
            int e4  = i * 256 + tid;       // float4 index within tile
            int row = e4 / 36;
            int c   = e4 - row * 36;       // float4-column 0..35
            float* p = &buf[(4 * c) * 64 + (row ^ c)];   // swz(4c+j) = c, j=0..3
            p[0]   = va[i].x;
            p[64]  = va[i].y;
            p[128] = va[i].z;
            p[192] = va[i].w;
        }

        // ---- issue next tile's global loads (hidden under compute+store) ----
        int tn = t + nb;
        if (tn < tiles)
            load_tile(feat4, (long long)tn * TILE_F4, total4, tid, vb);

        __syncthreads();

        // ---- compute: wave w owns units {w, w+4, w+8}; lane = row ----
        for (int p = w; p < 9; p += 4) {
            int d, tt, off;
            unit_params(p, d, tt, off);
            const float* __restrict__ C = Cw + p * 256;  // wave-uniform -> s_load

            float fin[16];
#pragma unroll
            for (int u = 0; u < 16; ++u) {
                int col = off + u * d + tt;
                fin[u] = buf[col * 64 + (r ^ (col >> 2))];
            }
            float acc[16];
#pragma unroll
            for (int vv = 0; vv < 16; ++vv) {
                float a = 0.0f;
#pragma unroll
                for (int u = 0; u < 16; ++u)
                    a += C[vv * 16 + u] * fin[u];
                acc[vv] = a;
            }
#pragma unroll
            for (int vv = 0; vv < 16; ++vv) {
                int col = off + vv * d + tt;
                buf[col * 64 + (r ^ (col >> 2))] = acc[vv];
            }
        }
        __syncthreads();

        // ---- stage out: swizzled b32 LDS reads, 9 coalesced float4 stores ----
        long long base4 = (long long)t * TILE_F4;
        bool full = (base4 + TILE_F4 <= total4);
#pragma unroll
        for (int i = 0; i < F4_PER_THREAD; ++i) {
            int e4  = i * 256 + tid;
            int row = e4 / 36;
            int c   = e4 - row * 36;
            const float* p = &buf[(4 * c) * 64 + (row ^ c)];
            float4 o = make_float4(p[0], p[64], p[128], p[192]);
            if (full) {
                out4[base4 + e4] = o;
            } else {
                long long g = base4 + e4;
                if (g < total4) out4[g] = o;
            }
        }

        __syncthreads();   // guard buf reuse before next iteration's stage-in

#pragma unroll
        for (int i = 0; i < F4_PER_THREAD; ++i) va[i] = vb[i];
    }
}

extern "C" void kernel_launch(void* const* d_in, const int* in_sizes, int n_in,
                              void* d_out, int out_size, void* d_ws, size_t ws_size,
                              hipStream_t stream)
{
    const float* feat   = (const float*)d_in[0];   // [B, 144]
    const float* weight = (const float*)d_in[1];   // [768]
    const float* mixing = (const float*)d_in[2];   // [768, 144, 144]
    const float* norm   = (const float*)d_in[3];   // [144, 144]
    float* out = (float*)d_out;
    float* Cw  = (float*)d_ws;                     // 9*256 floats

    long long total  = (long long)in_sizes[0];     // B * 144
    long long total4 = total / 4;                  // 144 % 4 == 0
    int nrows = (int)(total / DIM);
    int tiles = (nrows + ROWS - 1) / ROWS;
    int nb    = tiles < PERSIST_BLOCKS ? tiles : PERSIST_BLOCKS;

    build_C<<<9, 256, 0, stream>>>(weight, mixing, norm, Cw);
    tp_linear_kernel<<<nb, 256, 0, stream>>>(
        (const float4*)feat, Cw, (float4*)out, total4, tiles);
}